// Round 7
// baseline (137.101 us; speedup 1.0000x reference)
//
#include <hip/hip_runtime.h>
#include <hip/hip_bf16.h>
#include <math.h>

#define EPS 1e-6f
#define LOG2E 1.44269504088896340736f

typedef __attribute__((ext_vector_type(8))) short short8;
typedef __attribute__((ext_vector_type(4))) short short4v;
typedef __attribute__((ext_vector_type(4))) float f32x4;

// f32 -> bf16 (round-to-nearest-even)
static __device__ __forceinline__ short f2bf(float x) {
    unsigned u = __builtin_bit_cast(unsigned, x);
    u += 0x7fffu + ((u >> 16) & 1u);
    return (short)(u >> 16);
}

typedef __attribute__((address_space(1))) const void gvoid_t;
typedef __attribute__((address_space(3))) void lvoid_t;
static __device__ __forceinline__ void gload_lds16(const void* g, void* l) {
    __builtin_amdgcn_global_load_lds((gvoid_t*)g, (lvoid_t*)l, 16, 0, 0);
}

// ---------------------------------------------------------------------------
// x f32 -> bf16, 8 elems/thread
// ---------------------------------------------------------------------------
__global__ __launch_bounds__(256) void cast_f32_bf16(const float* __restrict__ src,
                                                     short* __restrict__ dst, int n8) {
    const int i = blockIdx.x * 256 + threadIdx.x;
    if (i >= n8) return;
    const float4 a = reinterpret_cast<const float4*>(src)[2 * i];
    const float4 b = reinterpret_cast<const float4*>(src)[2 * i + 1];
    short8 o;
    o[0] = f2bf(a.x); o[1] = f2bf(a.y); o[2] = f2bf(a.z); o[3] = f2bf(a.w);
    o[4] = f2bf(b.x); o[5] = f2bf(b.y); o[6] = f2bf(b.z); o[7] = f2bf(b.w);
    reinterpret_cast<short8*>(dst)[i] = o;
}

// ---------------------------------------------------------------------------
// All four weight transposes in ONE dispatch.
// ---------------------------------------------------------------------------
__global__ __launch_bounds__(256) void transpose_cast_all(
    const float* __restrict__ Wq, const float* __restrict__ Wk,
    const float* __restrict__ Wv, const float* __restrict__ Wo,
    short* __restrict__ WT, short* __restrict__ WoT) {
    __shared__ short tl[64][65];
    int t = blockIdx.x;
    const float* src; short* dst; int N, nx;
    if (t < 256)      { src = Wq; dst = WT;                N = 1024; nx = 16; }
    else if (t < 320) { src = Wk; dst = WT + 1024 * 1024;  N = 256;  nx = 4;  t -= 256; }
    else if (t < 384) { src = Wv; dst = WT + 1280 * 1024;  N = 256;  nx = 4;  t -= 320; }
    else              { src = Wo; dst = WoT;               N = 1024; nx = 16; t -= 384; }
    const int n0 = (t % nx) * 64, k0 = (t / nx) * 64;
    const int tid = threadIdx.x;

    #pragma unroll
    for (int i = 0; i < 4; ++i) {
        const int kr = (tid >> 4) + i * 16;
        const int c4 = (tid & 15) * 4;
        const float4 v = *reinterpret_cast<const float4*>(
            &src[(size_t)(k0 + kr) * N + n0 + c4]);
        tl[kr][c4 + 0] = f2bf(v.x);
        tl[kr][c4 + 1] = f2bf(v.y);
        tl[kr][c4 + 2] = f2bf(v.z);
        tl[kr][c4 + 3] = f2bf(v.w);
    }
    __syncthreads();

    const int nr  = tid >> 2;
    const int kc0 = (tid & 3) * 16;
    short tmp[16];
    #pragma unroll
    for (int j = 0; j < 16; ++j) tmp[j] = tl[kc0 + j][nr];
    short8* outp = reinterpret_cast<short8*>(&dst[(size_t)(n0 + nr) * 1024 + k0 + kc0]);
    outp[0] = *reinterpret_cast<short8*>(&tmp[0]);
    outp[1] = *reinterpret_cast<short8*>(&tmp[8]);
}

// ---------------------------------------------------------------------------
// bf16 MFMA GEMM: C[M,N] f32 = A[M,K] bf16 · B^T[N,K] bf16.  (unchanged)
// ---------------------------------------------------------------------------
__global__ __launch_bounds__(256) void gemm_bf16(const short* __restrict__ A,
                                                 const short* __restrict__ BT,
                                                 float* __restrict__ C,
                                                 int M, int N, int K) {
    __shared__ short As[2][128 * 32];
    __shared__ short Bs[2][128 * 32];

    const int tid  = threadIdx.x;
    const int lane = tid & 63;
    const int w    = tid >> 6;
    const int lq = lane & 15, lh = lane >> 4;
    const int wm = w >> 1,   wn = w & 1;
    const size_t arow0 = (size_t)blockIdx.y * 128;
    const size_t brow0 = (size_t)blockIdx.x * 128;

    f32x4 acc[4][4];
    #pragma unroll
    for (int mi = 0; mi < 4; ++mi)
        #pragma unroll
        for (int ni = 0; ni < 4; ++ni) acc[mi][ni] = (f32x4){0.f, 0.f, 0.f, 0.f};

    const int NT = K >> 5;
    int cur = 0;

    #pragma unroll
    for (int i = 0; i < 2; ++i) {
        const int ch = w * 64 + i * 256 + lane;
        const int r = ch >> 2, c = ch & 3;
        const int cg = c ^ ((r >> 1) & 3);
        gload_lds16(A + (arow0 + r) * K + cg * 8, &As[0][(w * 64 + i * 256) * 8]);
        gload_lds16(BT + (brow0 + r) * K + cg * 8, &Bs[0][(w * 64 + i * 256) * 8]);
    }
    __syncthreads();

    for (int t = 0; t < NT; ++t) {
        if (t + 1 < NT) {
            const int k0 = (t + 1) << 5;
            #pragma unroll
            for (int i = 0; i < 2; ++i) {
                const int ch = w * 64 + i * 256 + lane;
                const int r = ch >> 2, c = ch & 3;
                const int cg = c ^ ((r >> 1) & 3);
                gload_lds16(A + (arow0 + r) * K + k0 + cg * 8,
                            &As[cur ^ 1][(w * 64 + i * 256) * 8]);
                gload_lds16(BT + (brow0 + r) * K + k0 + cg * 8,
                            &Bs[cur ^ 1][(w * 64 + i * 256) * 8]);
            }
        }

        short8 af[4], bf[4];
        #pragma unroll
        for (int mi = 0; mi < 4; ++mi) {
            const int r = wm * 64 + mi * 16 + lq;
            af[mi] = *reinterpret_cast<const short8*>(
                &As[cur][r * 32 + ((lh ^ ((r >> 1) & 3)) * 8)]);
        }
        #pragma unroll
        for (int ni = 0; ni < 4; ++ni) {
            const int r = wn * 64 + ni * 16 + lq;
            bf[ni] = *reinterpret_cast<const short8*>(
                &Bs[cur][r * 32 + ((lh ^ ((r >> 1) & 3)) * 8)]);
        }
        #pragma unroll
        for (int mi = 0; mi < 4; ++mi)
            #pragma unroll
            for (int ni = 0; ni < 4; ++ni)
                acc[mi][ni] = __builtin_amdgcn_mfma_f32_16x16x32_bf16(
                    af[mi], bf[ni], acc[mi][ni], 0, 0, 0);

        __syncthreads();
        cur ^= 1;
    }

    #pragma unroll
    for (int mi = 0; mi < 4; ++mi) {
        const size_t row = arow0 + wm * 64 + mi * 16 + lh * 4;
        #pragma unroll
        for (int ni = 0; ni < 4; ++ni) {
            const size_t col = brow0 + wn * 64 + ni * 16 + lq;
            #pragma unroll
            for (int i = 0; i < 4; ++i)
                C[(row + i) * N + col] = acc[mi][ni][i];
        }
    }
}

// ---------------------------------------------------------------------------
// RoPE + RMSNorm on qkv f32 [B,T,1536] -> bf16 head-major.
// ---------------------------------------------------------------------------
__global__ __launch_bounds__(256) void rope_rmsnorm_cast(
    const float* __restrict__ qkv, const float* __restrict__ cosb,
    const float* __restrict__ sinb, short* __restrict__ q16,
    short* __restrict__ k16, int B, int T) {
    const int lane = threadIdx.x & 63;
    const int wid  = threadIdx.x >> 6;
    const int row  = blockIdx.x * 4 + wid;
    const int bt = row / 20;
    const int h  = row % 20;
    const int b  = bt / T, t = bt % T;

    const float* src = (h < 16) ? qkv + (size_t)bt * 1536 + h * 64
                                : qkv + (size_t)bt * 1536 + 1024 + (h - 16) * 64;

    const int j = lane & 31;
    const float x1 = src[j];
    const float x2 = src[j + 32];
    const float c = cosb[t * 32 + j];
    const float s = sinb[t * 32 + j];
    float y = (lane < 32) ? (x1 * c + x2 * s) : (x2 * c - x1 * s);

    float ss = y * y;
    #pragma unroll
    for (int m = 1; m < 64; m <<= 1) ss += __shfl_xor(ss, m);
    const float r = rsqrtf(ss * (1.0f / 64.0f) + EPS);

    if (h < 16)
        q16[((size_t)(b * 16 + h) * T + t) * 64 + lane] = f2bf(y * r * (0.125f * LOG2E));
    else
        k16[((size_t)(b * 4 + (h - 16)) * T + t) * 64 + lane] = f2bf(y * r);
}

// ---------------------------------------------------------------------------
// v slice of qkv -> bf16 transposed + key-permuted vT16 [B,4,64,T]
// ---------------------------------------------------------------------------
__global__ __launch_bounds__(256) void vcast_transpose(
    const float* __restrict__ qkv, short* __restrict__ vT, int B, int T) {
    __shared__ short tl[64][65];
    const int tid = threadIdx.x;
    const int b = blockIdx.z, kvh = blockIdx.y, t0 = blockIdx.x * 64;

    #pragma unroll
    for (int i = 0; i < 4; ++i) {
        const int tr = (tid >> 4) + i * 16;
        const int d4 = (tid & 15) * 4;
        const float4 v4 = *reinterpret_cast<const float4*>(
            &qkv[(size_t)(b * T + t0 + tr) * 1536 + 1280 + kvh * 64 + d4]);
        tl[tr][d4 + 0] = f2bf(v4.x);
        tl[tr][d4 + 1] = f2bf(v4.y);
        tl[tr][d4 + 2] = f2bf(v4.z);
        tl[tr][d4 + 3] = f2bf(v4.w);
    }
    __syncthreads();

    const int dim = tid >> 2;
    const int tq  = (tid & 3) * 16;
    const int hi  = (tq >> 4) & 1;
    const int a32 = tq & 32;
    short tmp[16];
    #pragma unroll
    for (int j2 = 0; j2 < 16; ++j2) tmp[j2] = tl[tq + j2][dim];
    short* orow = &vT[((size_t)(b * 4 + kvh) * 64 + dim) * T + t0];
    #pragma unroll
    for (int g = 0; g < 4; ++g) {
        *reinterpret_cast<short4v*>(orow + a32 + g * 8 + hi * 4) =
            *reinterpret_cast<short4v*>(&tmp[g * 4]);
    }
}

// exp2 + bf16-pack of one stream's scores (kmax-guarded)
static __device__ __forceinline__ void sm_pack(f32x4 (&st)[4], short8 (&pf)[2],
                                               const int kmax) {
    #pragma unroll
    for (int ks2 = 0; ks2 < 2; ++ks2) if (ks2 * 2 < kmax) {
        #pragma unroll
        for (int ks = 2 * ks2; ks < 2 * ks2 + 2; ++ks)
            #pragma unroll
            for (int i2 = 0; i2 < 4; ++i2)
                st[ks][i2] = exp2f(st[ks][i2]);
        union { short8 s8; __hip_bfloat162 h2[4]; } u;
        u.h2[0] = __float22bfloat162_rn(float2{st[2 * ks2][0], st[2 * ks2][1]});
        u.h2[1] = __float22bfloat162_rn(float2{st[2 * ks2][2], st[2 * ks2][3]});
        u.h2[2] = __float22bfloat162_rn(float2{st[2 * ks2 + 1][0], st[2 * ks2 + 1][1]});
        u.h2[3] = __float22bfloat162_rn(float2{st[2 * ks2 + 1][2], st[2 * ks2 + 1][3]});
        pf[ks2] = u.s8;
    }
}

// ---------------------------------------------------------------------------
// bf16 MFMA flash attention — static-max softmax + PAIRED q-tiles + 2-phase
// async staging. Block p of (b,h) owns q-tiles qlo=p and qhi=63-p (32 rows
// each; 2 waves x 16 rows). KV tiles staged once, consumed by both streams;
// kfr/vf LDS reads shared in registers. Double-buffered LDS; next tile's
// global_load_lds issued BEFORE current tile's compute (T3-minimum 2-phase).
// ---------------------------------------------------------------------------
__global__ __launch_bounds__(128) void attn_mfma(
    const short* __restrict__ q16, const short* __restrict__ k16,
    const short* __restrict__ vT16, short* __restrict__ att16, int B, int T) {
    __shared__ short Kt[2][64 * 64];
    __shared__ short Vt[2][64 * 64];

    const int tid  = threadIdx.x;
    const int lane = tid & 63;
    const int w    = tid >> 6;          // 0..1
    const int lq   = lane & 15;
    const int lh   = lane >> 4;

    const int idx = blockIdx.x;
    const int p   = idx & 31;           // pair index (fast dim -> L2 reuse)
    const int bh  = idx >> 5;
    const int b   = bh >> 4, h = bh & 15;
    const int hk  = h >> 2;
    const int NQ  = T >> 5;             // 64 q-tiles of 32 rows
    const int qlo = p, qhi = NQ - 1 - p;
    const int nt_lo = (qlo >> 1) + 1;
    const int nt_hi = (qhi >> 1) + 1;
    const int t_lo = qlo * 32 + w * 16;
    const int t_hi = qhi * 32 + w * 16;

    const short* qbase = q16 + (size_t)(b * 16 + h) * T * 64;
    const short8 qlo0 = *reinterpret_cast<const short8*>(qbase + (t_lo + lq) * 64 + lh * 8);
    const short8 qlo1 = *reinterpret_cast<const short8*>(qbase + (t_lo + lq) * 64 + 32 + lh * 8);
    const short8 qhi0 = *reinterpret_cast<const short8*>(qbase + (t_hi + lq) * 64 + lh * 8);
    const short8 qhi1 = *reinterpret_cast<const short8*>(qbase + (t_hi + lq) * 64 + 32 + lh * 8);

    const short* kgbase = k16 + (size_t)(b * 4 + hk) * T * 64;
    const short* vgbase = vT16 + (size_t)(b * 4 + hk) * 64 * T;

    const int sr  = lane >> 3;
    const int sc  = lane & 7;
    const int scg = sc ^ sr;            // pre-swizzled global chunk

    short8 ones;
    #pragma unroll
    for (int i = 0; i < 8; ++i) ones[i] = (short)0x3F80;

    f32x4 ylo[4], yhi[4];
    #pragma unroll
    for (int dt = 0; dt < 4; ++dt) {
        ylo[dt] = (f32x4){0.f, 0.f, 0.f, 0.f};
        yhi[dt] = (f32x4){0.f, 0.f, 0.f, 0.f};
    }
    f32x4 llo = (f32x4){0.f, 0.f, 0.f, 0.f};
    f32x4 lhi = (f32x4){0.f, 0.f, 0.f, 0.f};

    auto STAGE = [&](int u, int ti2) {
        const int s0 = ti2 * 64;
        #pragma unroll
        for (int p2 = 0; p2 < 4; ++p2) {
            const int r = w * 32 + p2 * 8 + sr;
            gload_lds16(kgbase + (size_t)(s0 + r) * 64 + scg * 8,
                        &Kt[u][(w * 32 + p2 * 8) * 64]);
            gload_lds16(vgbase + (size_t)r * T + s0 + scg * 8,
                        &Vt[u][(w * 32 + p2 * 8) * 64]);
        }
    };

    STAGE(0, 0);
    __syncthreads();
    int cur = 0;

    for (int ti = 0; ti < nt_hi; ++ti) {
        if (ti + 1 < nt_hi) STAGE(cur ^ 1, ti + 1);   // issue-early (2-phase)

        const bool lo_act  = (ti < nt_lo);
        const bool hi_last = (ti == nt_hi - 1);
        const bool lo_last = (ti == nt_lo - 1);
        const int kmax_hi = (hi_last && !(qhi & 1)) ? 2 : 4;
        const int kmax_lo = (lo_last && !(qlo & 1)) ? 2 : 4;
        const int kmaxr   = lo_act ? 4 : kmax_hi;     // reads cover active streams

        // --- shared K fragment reads ---
        short8 kfr[4][2];
        #pragma unroll
        for (int ks = 0; ks < 4; ++ks) if (ks < kmaxr)
            #pragma unroll
            for (int dk = 0; dk < 2; ++dk)
                kfr[ks][dk] = *reinterpret_cast<const short8*>(
                    (char*)Kt[cur] + (ks * 16 + lq) * 128 +
                    (((dk * 4 + lh) ^ (lq & 7)) * 16));

        // --- QK^T both streams ---
        f32x4 sthi[4], stlo[4];
        __builtin_amdgcn_s_setprio(1);
        #pragma unroll
        for (int ks = 0; ks < 4; ++ks) if (ks < kmax_hi) {
            f32x4 a1 = (f32x4){0.f, 0.f, 0.f, 0.f};
            a1 = __builtin_amdgcn_mfma_f32_16x16x32_bf16(kfr[ks][0], qhi0, a1, 0, 0, 0);
            a1 = __builtin_amdgcn_mfma_f32_16x16x32_bf16(kfr[ks][1], qhi1, a1, 0, 0, 0);
            sthi[ks] = a1;
        }
        if (lo_act) {
            #pragma unroll
            for (int ks = 0; ks < 4; ++ks) if (ks < kmax_lo) {
                f32x4 a1 = (f32x4){0.f, 0.f, 0.f, 0.f};
                a1 = __builtin_amdgcn_mfma_f32_16x16x32_bf16(kfr[ks][0], qlo0, a1, 0, 0, 0);
                a1 = __builtin_amdgcn_mfma_f32_16x16x32_bf16(kfr[ks][1], qlo1, a1, 0, 0, 0);
                stlo[ks] = a1;
            }
        }
        __builtin_amdgcn_s_setprio(0);

        // --- masks + softmax packs ---
        if (hi_last) {
            const int rloc = (qhi & 1) * 32 + w * 16 + lq;
            #pragma unroll
            for (int ks = 0; ks < 4; ++ks) if (ks < kmax_hi)
                #pragma unroll
                for (int i2 = 0; i2 < 4; ++i2)
                    if (ks * 16 + lh * 4 + i2 > rloc) sthi[ks][i2] = -1e30f;
        }
        short8 pfhi[2], pflo[2];
        sm_pack(sthi, pfhi, kmax_hi);
        if (lo_act) {
            if (lo_last) {
                const int rloc = (qlo & 1) * 32 + w * 16 + lq;
                #pragma unroll
                for (int ks = 0; ks < 4; ++ks) if (ks < kmax_lo)
                    #pragma unroll
                    for (int i2 = 0; i2 < 4; ++i2)
                        if (ks * 16 + lh * 4 + i2 > rloc) stlo[ks][i2] = -1e30f;
            }
            sm_pack(stlo, pflo, kmax_lo);
        }

        // --- shared V fragment reads ---
        short8 vf[4][2];
        #pragma unroll
        for (int dt = 0; dt < 4; ++dt) {
            const int rb = (dt * 16 + lq) * 128;
            const int sw = lq & 7;
            #pragma unroll
            for (int ks2 = 0; ks2 < 2; ++ks2) if (ks2 * 2 < kmaxr)
                vf[dt][ks2] = *reinterpret_cast<const short8*>(
                    (char*)Vt[cur] + rb + (((ks2 * 4 + lh) ^ sw) * 16));
        }

        // --- l + PV both streams ---
        __builtin_amdgcn_s_setprio(1);
        #pragma unroll
        for (int ks2 = 0; ks2 < 2; ++ks2) if (ks2 * 2 < kmax_hi)
            lhi = __builtin_amdgcn_mfma_f32_16x16x32_bf16(ones, pfhi[ks2], lhi, 0, 0, 0);
        #pragma unroll
        for (int dt = 0; dt < 4; ++dt)
            #pragma unroll
            for (int ks2 = 0; ks2 < 2; ++ks2) if (ks2 * 2 < kmax_hi)
                yhi[dt] = __builtin_amdgcn_mfma_f32_16x16x32_bf16(
                    vf[dt][ks2], pfhi[ks2], yhi[dt], 0, 0, 0);
        if (lo_act) {
            #pragma unroll
            for (int ks2 = 0; ks2 < 2; ++ks2) if (ks2 * 2 < kmax_lo)
                llo = __builtin_amdgcn_mfma_f32_16x16x32_bf16(ones, pflo[ks2], llo, 0, 0, 0);
            #pragma unroll
            for (int dt = 0; dt < 4; ++dt)
                #pragma unroll
                for (int ks2 = 0; ks2 < 2; ++ks2) if (ks2 * 2 < kmax_lo)
                    ylo[dt] = __builtin_amdgcn_mfma_f32_16x16x32_bf16(
                        vf[dt][ks2], pflo[ks2], ylo[dt], 0, 0, 0);
        }
        __builtin_amdgcn_s_setprio(0);

        __syncthreads();   // next buffer staged; everyone done with cur
        cur ^= 1;
    }

    // --- epilogues ---
    const float invh = 1.f / lhi[0];
    short* orowh = att16 + (((size_t)b * T + t_hi + lq) * 16 + h) * 64;
    #pragma unroll
    for (int dt = 0; dt < 4; ++dt) {
        short4v o;
        o[0] = f2bf(yhi[dt][0] * invh);
        o[1] = f2bf(yhi[dt][1] * invh);
        o[2] = f2bf(yhi[dt][2] * invh);
        o[3] = f2bf(yhi[dt][3] * invh);
        *reinterpret_cast<short4v*>(orowh + dt * 16 + lh * 4) = o;
    }
    const float invl = 1.f / llo[0];
    short* orowl = att16 + (((size_t)b * T + t_lo + lq) * 16 + h) * 64;
    #pragma unroll
    for (int dt = 0; dt < 4; ++dt) {
        short4v o;
        o[0] = f2bf(ylo[dt][0] * invl);
        o[1] = f2bf(ylo[dt][1] * invl);
        o[2] = f2bf(ylo[dt][2] * invl);
        o[3] = f2bf(ylo[dt][3] * invl);
        *reinterpret_cast<short4v*>(orowl + dt * 16 + lh * 4) = o;
    }
}

// ---------------------------------------------------------------------------
extern "C" void kernel_launch(void* const* d_in, const int* in_sizes, int n_in,
                              void* d_out, int out_size, void* d_ws, size_t ws_size,
                              hipStream_t stream) {
    const float* x    = (const float*)d_in[0];
    const float* cosb = (const float*)d_in[1];
    const float* sinb = (const float*)d_in[2];
    const float* Wq   = (const float*)d_in[3];
    const float* Wk   = (const float*)d_in[4];
    const float* Wv   = (const float*)d_in[5];
    const float* Wo   = (const float*)d_in[6];
    float* out = (float*)d_out;

    const int B = 2, T = 2048;
    const int M = B * T;   // 4096
    const size_t MB = 1 << 20;

    char* wsb = (char*)d_ws;
    float* qkv  = (float*)(wsb);
    short* att16= (short*)(wsb);
    short* x16  = (short*)(wsb + 24 * MB);
    short* q16  = (short*)(wsb + 24 * MB);
    short* WT   = (short*)(wsb + 32 * MB);
    short* k16  = (short*)(wsb + 32 * MB);
    short* vT16 = (short*)(wsb + 34 * MB);
    short* WoT  = (short*)(wsb + 36 * MB);

    cast_f32_bf16<<<(M * 1024 / 8 + 255) / 256, 256, 0, stream>>>(x, x16, M * 1024 / 8);
    transpose_cast_all<<<640, 256, 0, stream>>>(Wq, Wk, Wv, Wo, WT, WoT);

    gemm_bf16<<<dim3(1536 / 128, M / 128), 256, 0, stream>>>(x16, WT, qkv, M, 1536, 1024);

    rope_rmsnorm_cast<<<(B * T * 20) / 4, 256, 0, stream>>>(qkv, cosb, sinb, q16, k16, B, T);
    vcast_transpose<<<dim3(T / 64, 4, B), 256, 0, stream>>>(qkv, vT16, B, T);

    // paired static-max flash attention: 32 pairs x 32 (b,h) = 1024 blocks
    attn_mfma<<<dim3(32 * 16 * B), 128, 0, stream>>>(q16, k16, vT16, att16, B, T);

    gemm_bf16<<<dim3(1024 / 128, M / 128), 256, 0, stream>>>(att16, WoT, out, M, 1024, 1024);
}

// Round 8
// 124.729 us; speedup vs baseline: 1.0992x; 1.0992x over previous
//
#include <hip/hip_runtime.h>
#include <hip/hip_bf16.h>
#include <math.h>

#define EPS 1e-6f
#define LOG2E 1.44269504088896340736f

typedef __attribute__((ext_vector_type(8))) short short8;
typedef __attribute__((ext_vector_type(4))) short short4v;
typedef __attribute__((ext_vector_type(4))) float f32x4;

// f32 -> bf16 (round-to-nearest-even)
static __device__ __forceinline__ short f2bf(float x) {
    unsigned u = __builtin_bit_cast(unsigned, x);
    u += 0x7fffu + ((u >> 16) & 1u);
    return (short)(u >> 16);
}

typedef __attribute__((address_space(1))) const void gvoid_t;
typedef __attribute__((address_space(3))) void lvoid_t;
static __device__ __forceinline__ void gload_lds16(const void* g, void* l) {
    __builtin_amdgcn_global_load_lds((gvoid_t*)g, (lvoid_t*)l, 16, 0, 0);
}

// ---------------------------------------------------------------------------
// x f32 -> bf16, 8 elems/thread
// ---------------------------------------------------------------------------
__global__ __launch_bounds__(256) void cast_f32_bf16(const float* __restrict__ src,
                                                     short* __restrict__ dst, int n8) {
    const int i = blockIdx.x * 256 + threadIdx.x;
    if (i >= n8) return;
    const float4 a = reinterpret_cast<const float4*>(src)[2 * i];
    const float4 b = reinterpret_cast<const float4*>(src)[2 * i + 1];
    short8 o;
    o[0] = f2bf(a.x); o[1] = f2bf(a.y); o[2] = f2bf(a.z); o[3] = f2bf(a.w);
    o[4] = f2bf(b.x); o[5] = f2bf(b.y); o[6] = f2bf(b.z); o[7] = f2bf(b.w);
    reinterpret_cast<short8*>(dst)[i] = o;
}

// ---------------------------------------------------------------------------
// All four weight transposes in ONE dispatch.
// ---------------------------------------------------------------------------
__global__ __launch_bounds__(256) void transpose_cast_all(
    const float* __restrict__ Wq, const float* __restrict__ Wk,
    const float* __restrict__ Wv, const float* __restrict__ Wo,
    short* __restrict__ WT, short* __restrict__ WoT) {
    __shared__ short tl[64][65];
    int t = blockIdx.x;
    const float* src; short* dst; int N, nx;
    if (t < 256)      { src = Wq; dst = WT;                N = 1024; nx = 16; }
    else if (t < 320) { src = Wk; dst = WT + 1024 * 1024;  N = 256;  nx = 4;  t -= 256; }
    else if (t < 384) { src = Wv; dst = WT + 1280 * 1024;  N = 256;  nx = 4;  t -= 320; }
    else              { src = Wo; dst = WoT;               N = 1024; nx = 16; t -= 384; }
    const int n0 = (t % nx) * 64, k0 = (t / nx) * 64;
    const int tid = threadIdx.x;

    #pragma unroll
    for (int i = 0; i < 4; ++i) {
        const int kr = (tid >> 4) + i * 16;
        const int c4 = (tid & 15) * 4;
        const float4 v = *reinterpret_cast<const float4*>(
            &src[(size_t)(k0 + kr) * N + n0 + c4]);
        tl[kr][c4 + 0] = f2bf(v.x);
        tl[kr][c4 + 1] = f2bf(v.y);
        tl[kr][c4 + 2] = f2bf(v.z);
        tl[kr][c4 + 3] = f2bf(v.w);
    }
    __syncthreads();

    const int nr  = tid >> 2;
    const int kc0 = (tid & 3) * 16;
    short tmp[16];
    #pragma unroll
    for (int j = 0; j < 16; ++j) tmp[j] = tl[kc0 + j][nr];
    short8* outp = reinterpret_cast<short8*>(&dst[(size_t)(n0 + nr) * 1024 + k0 + kc0]);
    outp[0] = *reinterpret_cast<short8*>(&tmp[0]);
    outp[1] = *reinterpret_cast<short8*>(&tmp[8]);
}

// ---------------------------------------------------------------------------
// bf16 MFMA GEMM: C[M,N] f32 = A[M,K] bf16 · B^T[N,K] bf16.
// BM=128, BN=64, BK=32: more blocks (occupancy/balance) at our small N.
// 4 waves as 2M x 2N; wave tile 64x32; acc 4x2.
// ---------------------------------------------------------------------------
__global__ __launch_bounds__(256) void gemm_bf16(const short* __restrict__ A,
                                                 const short* __restrict__ BT,
                                                 float* __restrict__ C,
                                                 int M, int N, int K) {
    __shared__ short As[2][128 * 32];
    __shared__ short Bs[2][64 * 32];

    const int tid  = threadIdx.x;
    const int lane = tid & 63;
    const int w    = tid >> 6;
    const int lq = lane & 15, lh = lane >> 4;
    const int wm = w >> 1,   wn = w & 1;
    const size_t arow0 = (size_t)blockIdx.y * 128;
    const size_t brow0 = (size_t)blockIdx.x * 64;

    f32x4 acc[4][2];
    #pragma unroll
    for (int mi = 0; mi < 4; ++mi)
        #pragma unroll
        for (int ni = 0; ni < 2; ++ni) acc[mi][ni] = (f32x4){0.f, 0.f, 0.f, 0.f};

    const int NT = K >> 5;
    int cur = 0;

    auto STAGE = [&](int u, int k0) {
        // A tile: 128 rows x 32 k = 512 chunks; 2 per thread
        #pragma unroll
        for (int i = 0; i < 2; ++i) {
            const int ch = w * 64 + i * 256 + lane;
            const int r = ch >> 2, c = ch & 3;
            const int cg = c ^ ((r >> 1) & 3);
            gload_lds16(A + (arow0 + r) * K + k0 + cg * 8,
                        &As[u][(w * 64 + i * 256) * 8]);
        }
        // B tile: 64 rows x 32 k = 256 chunks; 1 per thread
        {
            const int r = tid >> 2, c = tid & 3;
            const int cg = c ^ ((r >> 1) & 3);
            gload_lds16(BT + (brow0 + r) * K + k0 + cg * 8, &Bs[u][tid * 8]);
        }
    };

    STAGE(0, 0);
    __syncthreads();

    for (int t = 0; t < NT; ++t) {
        if (t + 1 < NT) STAGE(cur ^ 1, (t + 1) << 5);

        short8 af[4], bf[2];
        #pragma unroll
        for (int mi = 0; mi < 4; ++mi) {
            const int r = wm * 64 + mi * 16 + lq;
            af[mi] = *reinterpret_cast<const short8*>(
                &As[cur][r * 32 + ((lh ^ ((r >> 1) & 3)) * 8)]);
        }
        #pragma unroll
        for (int ni = 0; ni < 2; ++ni) {
            const int r = wn * 32 + ni * 16 + lq;
            bf[ni] = *reinterpret_cast<const short8*>(
                &Bs[cur][r * 32 + ((lh ^ ((r >> 1) & 3)) * 8)]);
        }
        __builtin_amdgcn_s_setprio(1);
        #pragma unroll
        for (int mi = 0; mi < 4; ++mi)
            #pragma unroll
            for (int ni = 0; ni < 2; ++ni)
                acc[mi][ni] = __builtin_amdgcn_mfma_f32_16x16x32_bf16(
                    af[mi], bf[ni], acc[mi][ni], 0, 0, 0);
        __builtin_amdgcn_s_setprio(0);

        __syncthreads();
        cur ^= 1;
    }

    #pragma unroll
    for (int mi = 0; mi < 4; ++mi) {
        const size_t row = arow0 + wm * 64 + mi * 16 + lh * 4;
        #pragma unroll
        for (int ni = 0; ni < 2; ++ni) {
            const size_t col = brow0 + wn * 32 + ni * 16 + lq;
            #pragma unroll
            for (int i = 0; i < 4; ++i)
                C[(row + i) * N + col] = acc[mi][ni][i];
        }
    }
}

// ---------------------------------------------------------------------------
// RoPE + RMSNorm on qkv f32 [B,T,1536] -> bf16 head-major.
// ---------------------------------------------------------------------------
__global__ __launch_bounds__(256) void rope_rmsnorm_cast(
    const float* __restrict__ qkv, const float* __restrict__ cosb,
    const float* __restrict__ sinb, short* __restrict__ q16,
    short* __restrict__ k16, int B, int T) {
    const int lane = threadIdx.x & 63;
    const int wid  = threadIdx.x >> 6;
    const int row  = blockIdx.x * 4 + wid;
    const int bt = row / 20;
    const int h  = row % 20;
    const int b  = bt / T, t = bt % T;

    const float* src = (h < 16) ? qkv + (size_t)bt * 1536 + h * 64
                                : qkv + (size_t)bt * 1536 + 1024 + (h - 16) * 64;

    const int j = lane & 31;
    const float x1 = src[j];
    const float x2 = src[j + 32];
    const float c = cosb[t * 32 + j];
    const float s = sinb[t * 32 + j];
    float y = (lane < 32) ? (x1 * c + x2 * s) : (x2 * c - x1 * s);

    float ss = y * y;
    #pragma unroll
    for (int m = 1; m < 64; m <<= 1) ss += __shfl_xor(ss, m);
    const float r = rsqrtf(ss * (1.0f / 64.0f) + EPS);

    if (h < 16)
        q16[((size_t)(b * 16 + h) * T + t) * 64 + lane] = f2bf(y * r * (0.125f * LOG2E));
    else
        k16[((size_t)(b * 4 + (h - 16)) * T + t) * 64 + lane] = f2bf(y * r);
}

// ---------------------------------------------------------------------------
// v slice of qkv -> bf16 transposed + key-permuted vT16 [B,4,64,T]
// ---------------------------------------------------------------------------
__global__ __launch_bounds__(256) void vcast_transpose(
    const float* __restrict__ qkv, short* __restrict__ vT, int B, int T) {
    __shared__ short tl[64][65];
    const int tid = threadIdx.x;
    const int b = blockIdx.z, kvh = blockIdx.y, t0 = blockIdx.x * 64;

    #pragma unroll
    for (int i = 0; i < 4; ++i) {
        const int tr = (tid >> 4) + i * 16;
        const int d4 = (tid & 15) * 4;
        const float4 v4 = *reinterpret_cast<const float4*>(
            &qkv[(size_t)(b * T + t0 + tr) * 1536 + 1280 + kvh * 64 + d4]);
        tl[tr][d4 + 0] = f2bf(v4.x);
        tl[tr][d4 + 1] = f2bf(v4.y);
        tl[tr][d4 + 2] = f2bf(v4.z);
        tl[tr][d4 + 3] = f2bf(v4.w);
    }
    __syncthreads();

    const int dim = tid >> 2;
    const int tq  = (tid & 3) * 16;
    const int hi  = (tq >> 4) & 1;
    const int a32 = tq & 32;
    short tmp[16];
    #pragma unroll
    for (int j2 = 0; j2 < 16; ++j2) tmp[j2] = tl[tq + j2][dim];
    short* orow = &vT[((size_t)(b * 4 + kvh) * 64 + dim) * T + t0];
    #pragma unroll
    for (int g = 0; g < 4; ++g) {
        *reinterpret_cast<short4v*>(orow + a32 + g * 8 + hi * 4) =
            *reinterpret_cast<short4v*>(&tmp[g * 4]);
    }
}

// ---------------------------------------------------------------------------
// bf16 MFMA flash attention — static-max softmax (bounded scores: RMSNorm'd
// q,k => |s*log2e| <= 11.6 => p = exp2(s) directly; no running max/rescale).
// l via ones-fragment MFMA. 2-wave blocks, 32 q-rows, LPT grid. (R6 kernel.)
// ---------------------------------------------------------------------------
__global__ __launch_bounds__(128) void attn_mfma(
    const short* __restrict__ q16, const short* __restrict__ k16,
    const short* __restrict__ vT16, short* __restrict__ att16, int B, int T) {
    __shared__ short Kt[64 * 64];
    __shared__ short Vt[64 * 64];

    const int tid  = threadIdx.x;
    const int lane = tid & 63;
    const int w    = tid >> 6;          // 0..1
    const int lq   = lane & 15;
    const int lh   = lane >> 4;

    const int nbh = 16 * B;             // 32
    const int idx = blockIdx.x;
    const int qs  = (T >> 5) - 1 - idx / nbh;   // 63..0, longest-first
    const int bh  = idx % nbh;
    const int b   = bh >> 4, h = bh & 15;
    const int hk  = h >> 2;
    const int t0w = qs * 32 + w * 16;
    const int nt  = (qs >> 1) + 1;
    const bool evenq = !(qs & 1);       // last tile: keys 32..63 fully masked

    const short* qbase = q16 + (size_t)(b * 16 + h) * T * 64;
    const short8 qf0 = *reinterpret_cast<const short8*>(qbase + (t0w + lq) * 64 + lh * 8);
    const short8 qf1 = *reinterpret_cast<const short8*>(qbase + (t0w + lq) * 64 + 32 + lh * 8);

    const short* kgbase = k16 + (size_t)(b * 4 + hk) * T * 64;
    const short* vgbase = vT16 + (size_t)(b * 4 + hk) * 64 * T;

    const int sr  = lane >> 3;          // 0..7
    const int sc  = lane & 7;
    const int scg = sc ^ sr;            // pre-swizzled global chunk

    short8 ones;
    #pragma unroll
    for (int i = 0; i < 8; ++i) ones[i] = (short)0x3F80;   // bf16 1.0

    f32x4 yacc[4];
    #pragma unroll
    for (int dt = 0; dt < 4; ++dt) yacc[dt] = (f32x4){0.f, 0.f, 0.f, 0.f};
    f32x4 lacc = (f32x4){0.f, 0.f, 0.f, 0.f};

    for (int ti = 0; ti < nt; ++ti) {
        const int s0 = ti * 64;
        const bool last = (ti == nt - 1);
        const int kmax = (last && evenq) ? 2 : 4;   // skip fully-masked half
        __syncthreads();
        #pragma unroll
        for (int p2 = 0; p2 < 4; ++p2) {
            const int r = w * 32 + p2 * 8 + sr;
            gload_lds16(kgbase + (size_t)(s0 + r) * 64 + scg * 8,
                        &Kt[(w * 32 + p2 * 8) * 64]);
            gload_lds16(vgbase + (size_t)r * T + s0 + scg * 8,
                        &Vt[(w * 32 + p2 * 8) * 64]);
        }
        __syncthreads();

        // --- QK^T: S^T[key][q] (log2 units; scale folded into q) ---
        f32x4 st[4];
        __builtin_amdgcn_s_setprio(1);
        #pragma unroll
        for (int ks = 0; ks < 4; ++ks) if (ks < kmax) {
            f32x4 a1 = (f32x4){0.f, 0.f, 0.f, 0.f};
            #pragma unroll
            for (int dk = 0; dk < 2; ++dk) {
                const short8 kfr = *reinterpret_cast<const short8*>(
                    (char*)Kt + (ks * 16 + lq) * 128 +
                    (((dk * 4 + lh) ^ (lq & 7)) * 16));
                a1 = __builtin_amdgcn_mfma_f32_16x16x32_bf16(
                    kfr, dk ? qf1 : qf0, a1, 0, 0, 0);
            }
            st[ks] = a1;
        }
        __builtin_amdgcn_s_setprio(0);

        // --- causal mask on diagonal tile ---
        if (last) {
            const int rloc = (qs & 1) * 32 + w * 16 + lq;
            #pragma unroll
            for (int ks = 0; ks < 4; ++ks) if (ks < kmax)
                #pragma unroll
                for (int i2 = 0; i2 < 4; ++i2)
                    if (ks * 16 + lh * 4 + i2 > rloc)
                        st[ks][i2] = -1e30f;
        }

        // --- p = exp2(s) directly (bounded scores); pack to bf16 ---
        union { short8 s8; __hip_bfloat162 h2[4]; } pf[2];
        #pragma unroll
        for (int ks2 = 0; ks2 < 2; ++ks2) if (ks2 * 2 < kmax) {
            #pragma unroll
            for (int ks = 2 * ks2; ks < 2 * ks2 + 2; ++ks)
                #pragma unroll
                for (int i2 = 0; i2 < 4; ++i2)
                    st[ks][i2] = exp2f(st[ks][i2]);
            pf[ks2].h2[0] = __float22bfloat162_rn(float2{st[2 * ks2][0], st[2 * ks2][1]});
            pf[ks2].h2[1] = __float22bfloat162_rn(float2{st[2 * ks2][2], st[2 * ks2][3]});
            pf[ks2].h2[2] = __float22bfloat162_rn(float2{st[2 * ks2 + 1][0], st[2 * ks2 + 1][1]});
            pf[ks2].h2[3] = __float22bfloat162_rn(float2{st[2 * ks2 + 1][2], st[2 * ks2 + 1][3]});
        }

        // --- PV + l (ones-fragment MFMA) ---
        __builtin_amdgcn_s_setprio(1);
        #pragma unroll
        for (int ks2 = 0; ks2 < 2; ++ks2) if (ks2 * 2 < kmax)
            lacc = __builtin_amdgcn_mfma_f32_16x16x32_bf16(ones, pf[ks2].s8, lacc, 0, 0, 0);
        #pragma unroll
        for (int dt = 0; dt < 4; ++dt) {
            const int rb = (dt * 16 + lq) * 128;
            const int sw = lq & 7;
            #pragma unroll
            for (int ks2 = 0; ks2 < 2; ++ks2) if (ks2 * 2 < kmax) {
                const short8 vf = *reinterpret_cast<const short8*>(
                    (const char*)Vt + rb + (((ks2 * 4 + lh) ^ sw) * 16));
                yacc[dt] = __builtin_amdgcn_mfma_f32_16x16x32_bf16(
                    vf, pf[ks2].s8, yacc[dt], 0, 0, 0);
            }
        }
        __builtin_amdgcn_s_setprio(0);
    }

    // --- epilogue ---
    const float inv = 1.f / lacc[0];
    short* orow = att16 + (((size_t)b * T + t0w + lq) * 16 + h) * 64;
    #pragma unroll
    for (int dt = 0; dt < 4; ++dt) {
        short4v o;
        o[0] = f2bf(yacc[dt][0] * inv);
        o[1] = f2bf(yacc[dt][1] * inv);
        o[2] = f2bf(yacc[dt][2] * inv);
        o[3] = f2bf(yacc[dt][3] * inv);
        *reinterpret_cast<short4v*>(orow + dt * 16 + lh * 4) = o;
    }
}

// ---------------------------------------------------------------------------
extern "C" void kernel_launch(void* const* d_in, const int* in_sizes, int n_in,
                              void* d_out, int out_size, void* d_ws, size_t ws_size,
                              hipStream_t stream) {
    const float* x    = (const float*)d_in[0];
    const float* cosb = (const float*)d_in[1];
    const float* sinb = (const float*)d_in[2];
    const float* Wq   = (const float*)d_in[3];
    const float* Wk   = (const float*)d_in[4];
    const float* Wv   = (const float*)d_in[5];
    const float* Wo   = (const float*)d_in[6];
    float* out = (float*)d_out;

    const int B = 2, T = 2048;
    const int M = B * T;   // 4096
    const size_t MB = 1 << 20;

    char* wsb = (char*)d_ws;
    float* qkv  = (float*)(wsb);
    short* att16= (short*)(wsb);
    short* x16  = (short*)(wsb + 24 * MB);
    short* q16  = (short*)(wsb + 24 * MB);
    short* WT   = (short*)(wsb + 32 * MB);
    short* k16  = (short*)(wsb + 32 * MB);
    short* vT16 = (short*)(wsb + 34 * MB);
    short* WoT  = (short*)(wsb + 36 * MB);

    cast_f32_bf16<<<(M * 1024 / 8 + 255) / 256, 256, 0, stream>>>(x, x16, M * 1024 / 8);
    transpose_cast_all<<<640, 256, 0, stream>>>(Wq, Wk, Wv, Wo, WT, WoT);

    // QKV: BN=64 grid -> 24 x 32 = 768 blocks (3/CU exact)
    gemm_bf16<<<dim3(1536 / 64, M / 128), 256, 0, stream>>>(x16, WT, qkv, M, 1536, 1024);

    rope_rmsnorm_cast<<<(B * T * 20) / 4, 256, 0, stream>>>(qkv, cosb, sinb, q16, k16, B, T);
    vcast_transpose<<<dim3(T / 64, 4, B), 256, 0, stream>>>(qkv, vT16, B, T);

    // flash attention: 2-wave blocks, 32 q-rows each, LPT flat grid (R6)
    attn_mfma<<<dim3((T / 32) * 16 * B), 128, 0, stream>>>(q16, k16, vT16, att16, B, T);

    // Wo: 16 x 32 = 512 blocks (2/CU exact)
    gemm_bf16<<<dim3(1024 / 64, M / 128), 256, 0, stream>>>(att16, WoT, out, M, 1024, 1024);
}